// Round 19
// baseline (266.912 us; speedup 1.0000x reference)
//
#include <hip/hip_runtime.h>
#include <math.h>

#define EPSF 1e-5f
#define GAPTH 2e-4f     // MFMA logit err ~3e-6; 30-70x margin (0 flips observed)
#define NKS 2           // K-split slices for logits GEMM (576 each)
#define KSL 576
#define RROWS 18432

// B=128, C=8, H=144, W=144, CW=1152, R=18432, TW=5, OG=2, NCLS=6, DT=256, ITC=5760
// Collapsed head: logits[row, j] = sum_k Wc[j,k] * x'[row,k] + cconst[j]
// Pass 2 = pass 1 + rank-40 per-row delta, fused into softmax (DELTA=1).

typedef __attribute__((ext_vector_type(8))) short short8v;
typedef __attribute__((ext_vector_type(4))) short short4v;
typedef __attribute__((ext_vector_type(4))) float f32x4;
typedef unsigned short ushort;
typedef unsigned int uint;

__device__ inline ushort f2bf(float f) {
    uint u = __float_as_uint(f);
    uint r = (u + 0x7FFFu + ((u >> 16) & 1u)) >> 16;
    return (ushort)r;
}
__device__ inline float bf2f(ushort h) { return __uint_as_float(((uint)h) << 16); }

// ---------------------------------------------------------------------------
// Build combined weights, K-split over blockIdx.y; ILP-4 o-loop.
// Also zeroes cand_count (folded zero_counters dispatch).
// ---------------------------------------------------------------------------
__global__ __launch_bounds__(256) void wcomb_build(
    const float* __restrict__ w1e, const float* __restrict__ b1e, const float* __restrict__ ge,
    const float* __restrict__ bbe, const float* __restrict__ me, const float* __restrict__ ve,
    const float* __restrict__ w2e, const float* __restrict__ b2e,
    const float* __restrict__ w1c, const float* __restrict__ b1c, const float* __restrict__ gc,
    const float* __restrict__ bbc, const float* __restrict__ mc, const float* __restrict__ vc,
    const float* __restrict__ w2c, const float* __restrict__ b2c,
    float* __restrict__ Wc32, ushort* __restrict__ Wchi, ushort* __restrict__ Wclo,
    float* __restrict__ cconst, int* __restrict__ cand_count)
{
    __shared__ float coef[256];
    __shared__ float csum[4];
    const int j = blockIdx.x, kq = blockIdx.y, tid = threadIdx.x;
    const int lane = tid & 63, wid = tid >> 6;

    if (j == 0 && kq == 0 && tid == 0) *cand_count = 0;

    const float *w1 = nullptr, *w2row = nullptr, *b1 = nullptr, *g = nullptr,
                *bb = nullptr, *m = nullptr, *v = nullptr;
    float b2v = 0.f;
    int valid = 0;
    if (j < 144) {
        valid = 1; w1 = w1c; w2row = w2c + (size_t)j * 256;
        b1 = b1c; g = gc; bb = bbc; m = mc; v = vc; b2v = b2c[j];
    } else if (j < 146) {
        valid = 1; w1 = w1e; w2row = w2e + (size_t)(j - 144) * 256;
        b1 = b1e; g = ge; bb = bbe; m = me; v = ve; b2v = b2e[j - 144];
    }

    float cf = 0.f, cc = 0.f;
    if (valid) {
        float s = g[tid] * rsqrtf(v[tid] + EPSF);
        float w2v = w2row[tid];
        cf = w2v * s;
        cc = w2v * ((b1[tid] - m[tid]) * s + bb[tid]);
    }
    coef[tid] = cf;
    if (kq == 0) {
        float t = cc;
#pragma unroll
        for (int off = 32; off; off >>= 1) t += __shfl_xor(t, off);
        if (lane == 0) csum[wid] = t;
    }
    __syncthreads();
    if (kq == 0 && tid == 0)
        cconst[j] = valid ? ((csum[0] + csum[1]) + (csum[2] + csum[3]) + b2v) : 0.f;

    for (int k = kq * 288 + tid; k < (kq + 1) * 288; k += 256) {
        float acc = 0.f;
        if (valid) {
            float a0 = 0.f, a1 = 0.f, a2 = 0.f, a3 = 0.f;
            for (int o = 0; o < 256; o += 4) {
                a0 += coef[o]     * w1[(size_t)o * 1152 + k];
                a1 += coef[o + 1] * w1[(size_t)(o + 1) * 1152 + k];
                a2 += coef[o + 2] * w1[(size_t)(o + 2) * 1152 + k];
                a3 += coef[o + 3] * w1[(size_t)(o + 3) * 1152 + k];
            }
            acc = (a0 + a1) + (a2 + a3);
        }
        Wc32[(size_t)j * 1152 + k] = acc;
        ushort hi = f2bf(acc);
        Wchi[(size_t)j * 1152 + k] = hi;
        Wclo[(size_t)j * 1152 + k] = f2bf(acc - bf2f(hi));
    }
}

// ---------------------------------------------------------------------------
// three tiled transposes in one launch (blockIdx.z selects)
// ---------------------------------------------------------------------------
__global__ __launch_bounds__(256) void transpose3(
    const float* __restrict__ s0, float* __restrict__ d0,
    const float* __restrict__ s1, float* __restrict__ d1,
    const float* __restrict__ s2, float* __restrict__ d2)
{
    const float* src; float* dst; int R, Cc;
    if (blockIdx.z == 0)      { src = s0; dst = d0; R = 256; Cc = 1152; }
    else if (blockIdx.z == 1) { src = s1; dst = d1; R = 144; Cc = 256;
                                if (blockIdx.x >= 8 || blockIdx.y >= 5) return; }
    else                      { src = s2; dst = d2; R = 160; Cc = 1152;
                                if (blockIdx.y >= 5) return; }
    __shared__ float tile[32][33];
    const int rb = blockIdx.y * 32, cb = blockIdx.x * 32;
    const int tx = threadIdx.x & 31, ty = threadIdx.x >> 5;
#pragma unroll
    for (int i = ty; i < 32; i += 8) {
        int r = rb + i, c = cb + tx;
        tile[i][tx] = (r < R && c < Cc) ? src[(size_t)r * Cc + c] : 0.f;
    }
    __syncthreads();
#pragma unroll
    for (int i = ty; i < 32; i += 8) {
        int c = cb + i, r = rb + tx;
        if (c < Cc && r < R) dst[(size_t)c * R + r] = tile[tx][i];
    }
}

// ---------------------------------------------------------------------------
// logits GEMM: M=18432, N=160(146 used), K=1152 in NKS=2 slices of 576.
// BM=64, BN=160, BK=32; **8 waves (512 thr) as 4m x 2n**; wave tile 16x80.
// Same per-output product order as the 256-thr version -> bit-identical.
// 4608 waves total = 18/CU: cross-block TLP hides the barrier drain without
// increasing per-block B-staging (round-14's failure mode).
// LOAD(t+1) after barrier1 overlaps the MFMA section.
// ---------------------------------------------------------------------------
__global__ __launch_bounds__(512) void logits_gemm(
    const float* __restrict__ x, const ushort* __restrict__ Wchi, const ushort* __restrict__ Wclo,
    float* __restrict__ logits_part)
{
    __shared__ ushort Ahi[64][40], Alo[64][40], Bhi[160][40], Blo[160][40];
    const int tid = threadIdx.x;
    const int lane = tid & 63, wid = tid >> 6;
    const int wm = wid & 3, wn = wid >> 2;       // 4m x 2n
    const int rb = blockIdx.x * 64;
    const int ks = blockIdx.y;
    const int kbase = ks * KSL;
    const int NIT = KSL / 32;                    // 18

    // A staging: thread loads one float4: row tid>>3, k offset (tid&7)*4
    const int arl = tid >> 3, akk = (tid & 7) << 2;
    const int arow = rb + arl;
    const int ab = arow / 144, ahh = arow - ab * 144;

    // B staging: rows 0..127 by all 512 (8 ushorts); rows 128..159 by tid<128
    const int br0 = tid >> 2, bk0 = (tid & 3) << 3;
    const int br2 = 128 + (tid >> 2), bk2 = (tid & 3) << 3;

    float av[4];
    short8v vbh0, vbl0, vbh2, vbl2;

    auto LOAD = [&](int kb) {
        int k1 = kb + akk, c1 = k1 / 144, w1 = k1 - c1 * 144;   // 4-chunk stays in one c
        const float4 t0 = *reinterpret_cast<const float4*>(
            x + (((size_t)(ab * 8 + c1) * 144 + ahh) * 144 + w1));
        av[0] = t0.x; av[1] = t0.y; av[2] = t0.z; av[3] = t0.w;
        size_t o0 = (size_t)br0 * 1152 + kb + bk0;
        vbh0 = *reinterpret_cast<const short8v*>(Wchi + o0);
        vbl0 = *reinterpret_cast<const short8v*>(Wclo + o0);
        if (tid < 128) {
            size_t o2 = (size_t)br2 * 1152 + kb + bk2;
            vbh2 = *reinterpret_cast<const short8v*>(Wchi + o2);
            vbl2 = *reinterpret_cast<const short8v*>(Wclo + o2);
        }
    };

    auto STORE = [&]() {
        short4v hv, lv;
#pragma unroll
        for (int q = 0; q < 4; q++) {
            ushort h = f2bf(av[q]);
            hv[q] = (short)h;
            lv[q] = (short)f2bf(av[q] - bf2f(h));
        }
        *reinterpret_cast<short4v*>(&Ahi[arl][akk]) = hv;
        *reinterpret_cast<short4v*>(&Alo[arl][akk]) = lv;
        *reinterpret_cast<short8v*>(&Bhi[br0][bk0]) = vbh0;
        *reinterpret_cast<short8v*>(&Blo[br0][bk0]) = vbl0;
        if (tid < 128) {
            *reinterpret_cast<short8v*>(&Bhi[br2][bk2]) = vbh2;
            *reinterpret_cast<short8v*>(&Blo[br2][bk2]) = vbl2;
        }
    };

    f32x4 acc[5];
#pragma unroll
    for (int nt = 0; nt < 5; nt++) acc[nt] = (f32x4){0.f, 0.f, 0.f, 0.f};

    const int fr = lane & 15, fg = (lane >> 4) << 3;

    LOAD(kbase);
    for (int t = 0; t < NIT; t++) {
        STORE();
        __syncthreads();
        if (t < NIT - 1) LOAD(kbase + (t + 1) * 32);   // overlaps MFMA below
        short8v ah = *reinterpret_cast<const short8v*>(&Ahi[wm * 16 + fr][fg]);
        short8v al = *reinterpret_cast<const short8v*>(&Alo[wm * 16 + fr][fg]);
#pragma unroll
        for (int nt = 0; nt < 5; nt++) {
            short8v bh = *reinterpret_cast<const short8v*>(&Bhi[wn * 80 + nt * 16 + fr][fg]);
            short8v bl = *reinterpret_cast<const short8v*>(&Blo[wn * 80 + nt * 16 + fr][fg]);
            acc[nt] = __builtin_amdgcn_mfma_f32_16x16x32_bf16(ah, bh, acc[nt], 0, 0, 0);
            acc[nt] = __builtin_amdgcn_mfma_f32_16x16x32_bf16(ah, bl, acc[nt], 0, 0, 0);
            acc[nt] = __builtin_amdgcn_mfma_f32_16x16x32_bf16(al, bh, acc[nt], 0, 0, 0);
        }
        __syncthreads();
    }

    // epilogue: C/D layout col=lane&15, row=(lane>>4)*4+i  [m89-verified]
    float* base = logits_part + (size_t)ks * RROWS * 160;
    const int orow = rb + wm * 16 + ((lane >> 4) << 2);
#pragma unroll
    for (int nt = 0; nt < 5; nt++) {
        int gcol = wn * 80 + nt * 16 + fr;
        if (gcol < 146) {
            float* dst = base + (size_t)orow * 160 + gcol;
#pragma unroll
            for (int i = 0; i < 4; i++)
                dst[(size_t)i * 160] = acc[nt][i];
        }
    }
}

// ---------------------------------------------------------------------------
// merged softmax over summed K-slices; DELTA=1 adds rank-40 per-row patch delta.
// ---------------------------------------------------------------------------
template<int DELTA>
__global__ __launch_bounds__(256) void softmax_heads(
    const float* __restrict__ logits_part, const float* __restrict__ cconst,
    float* __restrict__ out_cls, float* __restrict__ out_ext,
    int* __restrict__ amax, float* __restrict__ partials,
    int* __restrict__ cand_count, int* __restrict__ cand_list,
    const float* __restrict__ x, const float* __restrict__ WcT,
    const float* __restrict__ refined5, const int* __restrict__ flag)
{
    __shared__ float ps[4];
    __shared__ float dL[4][148];
    __shared__ float dsh[4][40];
    __shared__ int   ksh[4][40];
    const int r4 = threadIdx.x >> 6, lane = threadIdx.x & 63;
    const int row = blockIdx.x * 4 + r4;

    if (DELTA) {
        const int fl = *flag;
        if (fl) {
            const int b = row / 144, hh = row - b * 144;
            const int a = amax[row];
            if (lane < 40) {
                int c = lane / 5, tw = lane - c * 5;
                int w = a - 2 + tw;
                float d = 0.f; int k = 0;
                if (w >= 0 && w < 144) {
                    k = c * 144 + w;
                    d = refined5[(size_t)b * 5760 + (c * 144 + hh) * 5 + tw]
                      - x[((size_t)(b * 8 + c) * 144 + hh) * 144 + w];
                }
                dsh[r4][lane] = d; ksh[r4][lane] = k;
            }
            __syncthreads();
#pragma unroll
            for (int rj = 0; rj < 3; rj++) {
                int j = lane + rj * 64;
                if (j < 146) {
                    float acc = 0.f;
#pragma unroll 8
                    for (int i = 0; i < 40; i++)
                        acc += WcT[(size_t)ksh[r4][i] * 160 + j] * dsh[r4][i];
                    dL[r4][j] = acc;
                }
            }
        } else {
#pragma unroll
            for (int rj = 0; rj < 3; rj++) {
                int j = lane + rj * 64;
                if (j < 146) dL[r4][j] = 0.f;
            }
        }
        __syncthreads();
    }

    const float* L0 = logits_part + (size_t)row * 160;
    const float* L1 = L0 + (size_t)RROWS * 160;
    float v0 = L0[lane] + L1[lane] + cconst[lane];
    float v1 = L0[lane + 64] + L1[lane + 64] + cconst[lane + 64];
    float v2 = (lane < 16) ? (L0[lane + 128] + L1[lane + 128] + cconst[lane + 128])
                           : -3.0e38f;
    if (DELTA) {
        v0 += dL[r4][lane];
        v1 += dL[r4][lane + 64];
        if (lane < 16) v2 += dL[r4][lane + 128];
    }
    float m = v0; int mi = lane;
    if (v1 > m) { m = v1; mi = lane + 64; }
    if (v2 > m) { m = v2; mi = lane + 128; }
    float m1 = v0, m2 = -3.0e38f;
    if (v1 > m1) { m2 = m1; m1 = v1; } else m2 = v1;
    if (v2 > m1) { m2 = m1; m1 = v2; } else m2 = fmaxf(m2, v2);
#pragma unroll
    for (int off = 32; off; off >>= 1) {
        float om = __shfl_xor(m, off);
        int   oi = __shfl_xor(mi, off);
        if (om > m || (om == m && oi < mi)) { m = om; mi = oi; }
        float om1 = __shfl_xor(m1, off);
        float om2 = __shfl_xor(m2, off);
        float nm1 = fmaxf(m1, om1);
        m2 = fmaxf(fminf(m1, om1), fmaxf(m2, om2));
        m1 = nm1;
    }
    float e0 = expf(v0 - m), e1 = expf(v1 - m);
    float e2 = (lane < 16) ? expf(v2 - m) : 0.f;
    float s = e0 + e1 + e2;
#pragma unroll
    for (int off = 32; off; off >>= 1) s += __shfl_xor(s, off);
    float inv = 1.f / s;
    float* O = out_cls + (size_t)row * 144;
    O[lane] = e0 * inv;
    O[lane + 64] = e1 * inv;
    if (lane < 16) O[lane + 128] = e2 * inv;

    float l0 = L0[144] + L1[144] + cconst[144];
    float l1 = L0[145] + L1[145] + cconst[145];
    if (DELTA) { l0 += dL[r4][144]; l1 += dL[r4][145]; }
    float mx = fmaxf(l0, l1);
    float ee0 = expf(l0 - mx), ee1 = expf(l1 - mx);
    float einv = 1.f / (ee0 + ee1);
    float p0 = ee0 * einv;
    if (lane == 0) {
        out_ext[(size_t)row * 2] = p0;
        out_ext[(size_t)row * 2 + 1] = ee1 * einv;
        if (amax != nullptr && !DELTA) {
            amax[row] = mi;
            if (m1 - m2 < GAPTH) {
                int slot = atomicAdd(cand_count, 1);
                cand_list[slot] = row;
            }
        }
    }
    if (partials != nullptr) {
        if (lane == 0) ps[r4] = p0;
        __syncthreads();
        if (threadIdx.x == 0) partials[blockIdx.x] = (ps[0] + ps[1]) + (ps[2] + ps[3]);
    }
}

__global__ __launch_bounds__(256) void reduce_flag(const float* __restrict__ partials, int n,
                                                   int* __restrict__ flag)
{
    __shared__ float sm[256];
    int tid = threadIdx.x;
    float s = 0.f;
    for (int i = tid; i < n; i += 256) s += partials[i];
    sm[tid] = s; __syncthreads();
    for (int off = 128; off; off >>= 1) {
        if (tid < off) sm[tid] += sm[tid + off];
        __syncthreads();
    }
    if (tid == 0) *flag = (sm[0] * (1.f / 18432.f) > 0.3f) ? 1 : 0;
}

// ---------------------------------------------------------------------------
// fixup over compacted candidate list: exact f32 two-stage recompute of argmax.
// ---------------------------------------------------------------------------
__global__ __launch_bounds__(256) void fixup_list(
    const int* __restrict__ cand_count, const int* __restrict__ cand_list,
    const float* __restrict__ x,
    const float* __restrict__ w1cT, const float* __restrict__ b1c,
    const float* __restrict__ gc, const float* __restrict__ bbc,
    const float* __restrict__ mc, const float* __restrict__ vc,
    const float* __restrict__ w2cT, const float* __restrict__ b2c,
    int* __restrict__ amax)
{
    __shared__ float xrow[1152];
    __shared__ float hsh[256];
    __shared__ float Lsh[144];
    const int tid = threadIdx.x;
    const int n = *cand_count;

    for (int ci = blockIdx.x; ci < n; ci += gridDim.x) {
        const int row = cand_list[ci];
        const int b = row / 144, hh = row - b * 144;
        for (int e = tid; e < 1152; e += 256) {
            int c = e / 144, w = e - c * 144;
            xrow[e] = x[(((size_t)(b * 8 + c) * 144 + hh) * 144) + w];
        }
        __syncthreads();
        {
            float a0 = 0.f, a1 = 0.f, a2 = 0.f, a3 = 0.f;
#pragma unroll 4
            for (int k = 0; k < 1152; k += 4) {
                a0 += w1cT[(size_t)k * 256 + tid] * xrow[k];
                a1 += w1cT[(size_t)(k + 1) * 256 + tid] * xrow[k + 1];
                a2 += w1cT[(size_t)(k + 2) * 256 + tid] * xrow[k + 2];
                a3 += w1cT[(size_t)(k + 3) * 256 + tid] * xrow[k + 3];
            }
            float a = (a0 + a1) + (a2 + a3);
            float sc = gc[tid] * rsqrtf(vc[tid] + EPSF);
            hsh[tid] = (a + b1c[tid] - mc[tid]) * sc + bbc[tid];
        }
        __syncthreads();
        if (tid < 144) {
            float a0 = 0.f, a1 = 0.f, a2 = 0.f, a3 = 0.f;
#pragma unroll 4
            for (int k = 0; k < 256; k += 4) {
                a0 += w2cT[(size_t)k * 144 + tid] * hsh[k];
                a1 += w2cT[(size_t)(k + 1) * 144 + tid] * hsh[k + 1];
                a2 += w2cT[(size_t)(k + 2) * 144 + tid] * hsh[k + 2];
                a3 += w2cT[(size_t)(k + 3) * 144 + tid] * hsh[k + 3];
            }
            Lsh[tid] = (a0 + a1) + (a2 + a3) + b2c[tid];
        }
        __syncthreads();
        if (tid == 0) {
            int bi = 0; float bv = Lsh[0];
            for (int j = 1; j < 144; j++) if (Lsh[j] > bv) { bv = Lsh[j]; bi = j; }
            amax[row] = bi;
        }
        __syncthreads();
    }
}

// ---------------------------------------------------------------------------
// tok GEMM with fused patch gather; 4 accumulators for ILP.
// ---------------------------------------------------------------------------
__global__ __launch_bounds__(256) void tok_partial(const float* __restrict__ x,
    const int* __restrict__ amax, const float* __restrict__ tok_w, float* __restrict__ tpart)
{
    __shared__ float P[720];
    __shared__ int ash[144];
    int b = blockIdx.x, c = blockIdx.y, tid = threadIdx.x;
    if (tid < 144) ash[tid] = amax[b * 144 + tid];
    __syncthreads();
    for (int e = tid; e < 720; e += 256) {
        int hh = e / 5, tw = e - hh * 5;
        int w = ash[hh] + tw - 2;
        P[e] = (w >= 0 && w < 144) ? x[(((size_t)(b * 8 + c) * 144 + hh) * 144) + w] : 0.f;
    }
    __syncthreads();
    const float* wbase = tok_w + (size_t)c * 720 * 256;
    float a0 = 0.f, a1 = 0.f, a2 = 0.f, a3 = 0.f;
    for (int k = 0; k < 720; k += 4) {
        a0 += P[k]     * wbase[(size_t)k * 256 + tid];
        a1 += P[k + 1] * wbase[(size_t)(k + 1) * 256 + tid];
        a2 += P[k + 2] * wbase[(size_t)(k + 2) * 256 + tid];
        a3 += P[k + 3] * wbase[(size_t)(k + 3) * 256 + tid];
    }
    tpart[((size_t)b * 8 + c) * 256 + tid] = (a0 + a1) + (a2 + a3);
}

// ---------------------------------------------------------------------------
// qkv_gemm (fused prep): grid (128,7). Each block sums tpart -> token base s,
// does LN1 for its token in-LDS, then its qkv slice. y<6: k/v cols 64..191
// for token y; y==6: q cols 0..63 for token 5 (also writes sbuf).
// ---------------------------------------------------------------------------
__global__ __launch_bounds__(256) void qkv_gemm(
    const float* __restrict__ tpart, const float* __restrict__ tok_b,
    const float* __restrict__ emb,
    const float* __restrict__ ln1_g, const float* __restrict__ ln1_b,
    const float* __restrict__ qkv_w,
    float* __restrict__ qkbuf, float* __restrict__ sbuf)
{
    __shared__ float zrow[256];
    __shared__ float r8[8];
    const int b = blockIdx.x, y = blockIdx.y, tid = threadIdx.x;
    const int i = (y < 6) ? y : 5;
    const int lane = tid & 63, wv = tid >> 6;
    const int g4 = tid >> 2, l4 = tid & 3;

    float a = tok_b[tid];
#pragma unroll
    for (int ks = 0; ks < 8; ks++) a += tpart[((size_t)b * 8 + ks) * 256 + tid];
    if (y == 6) sbuf[(size_t)b * 256 + tid] = a;

    float v = a + emb[i * 256 + tid];
    float s1 = v, s2 = v * v;
#pragma unroll
    for (int off = 32; off; off >>= 1) { s1 += __shfl_down(s1, off); s2 += __shfl_down(s2, off); }
    if (lane == 0) { r8[wv * 2] = s1; r8[wv * 2 + 1] = s2; }
    __syncthreads();
    float t1 = (r8[0] + r8[2]) + (r8[4] + r8[6]);
    float t2 = (r8[1] + r8[3]) + (r8[5] + r8[7]);
    float mu = t1 * (1.f / 256.f);
    float var = t2 * (1.f / 256.f) - mu * mu;
    zrow[tid] = (v - mu) * rsqrtf(var + EPSF) * ln1_g[tid] + ln1_b[tid];
    __syncthreads();

    if (y < 6) {
        for (int tt = g4; tt < 128; tt += 64) {
            const int c = 64 + tt;
            float acc = 0.f;
#pragma unroll 8
            for (int j = 0; j < 64; j++) {
                int k = l4 + 4 * j;
                acc += zrow[k] * qkv_w[(size_t)k * 192 + c];
            }
            acc += __shfl_xor(acc, 1);
            acc += __shfl_xor(acc, 2);
            if (l4 == 0) qkbuf[((size_t)b * 6 + i) * 192 + c] = acc;
        }
    } else {
        const int c = g4;   // 0..63
        float acc = 0.f;
#pragma unroll 8
        for (int j = 0; j < 64; j++) {
            int k = l4 + 4 * j;
            acc += zrow[k] * qkv_w[(size_t)k * 192 + c];
        }
        acc += __shfl_xor(acc, 1);
        acc += __shfl_xor(acc, 2);
        if (l4 == 0) qkbuf[((size_t)b * 6 + 5) * 192 + c] = acc;
    }
}

// ---------------------------------------------------------------------------
// attn_out: attention row 5 + out-proj + residual + LN2 -> z2_5, t5buf.
// ---------------------------------------------------------------------------
__global__ __launch_bounds__(256) void attn_out(
    const float* __restrict__ qkbuf, const float* __restrict__ sbuf,
    const float* __restrict__ emb,
    const float* __restrict__ out_w, const float* __restrict__ out_b,
    const float* __restrict__ ln2_g, const float* __restrict__ ln2_b,
    float* __restrict__ z2_5, float* __restrict__ t5buf)
{
    __shared__ float qk[6][192];
    __shared__ float att[2][6];
    __shared__ float o5[64];
    __shared__ float t5[256];
    __shared__ float stat[2];
    const int b = blockIdx.x, tid = threadIdx.x;
    const int lane = tid & 63, wv = tid >> 6;
    const int g4 = tid >> 2, l4 = tid & 3;

    for (int e = tid; e < 1152; e += 256)
        qk[e / 192][e - (e / 192) * 192] = qkbuf[(size_t)b * 1152 + e];
    __syncthreads();

    if (tid < 12) {
        int h = tid / 6, j = tid - h * 6;
        float a = 0.f;
#pragma unroll
        for (int d = 0; d < 32; d++) a += qk[5][h * 32 + d] * qk[j][64 + h * 32 + d];
        att[h][j] = a * 0.17677669529663687f;
    }
    __syncthreads();
    if (tid < 2) {
        float m = -3.0e38f;
        for (int j = 0; j < 6; j++) m = fmaxf(m, att[tid][j]);
        float ssum = 0.f;
        for (int j = 0; j < 6; j++) { float e = expf(att[tid][j] - m); att[tid][j] = e; ssum += e; }
        float inv = 1.f / ssum;
        for (int j = 0; j < 6; j++) att[tid][j] *= inv;
    }
    __syncthreads();
    if (tid < 64) {
        int h = tid >> 5;
        float a = 0.f;
#pragma unroll
        for (int j = 0; j < 6; j++) a += att[h][j] * qk[j][128 + tid];
        o5[tid] = a;
    }
    __syncthreads();

    for (int tt = g4; tt < 256; tt += 64) {
        float a = 0.f;
#pragma unroll
        for (int j = 0; j < 16; j++) {
            int d = l4 + 4 * j;
            a += o5[d] * out_w[(size_t)d * 256 + tt];
        }
        a += __shfl_xor(a, 1);
        a += __shfl_xor(a, 2);
        if (l4 == 0)
            t5[tt] = a + out_b[tt] + sbuf[(size_t)b * 256 + tt] + emb[5 * 256 + tt];
    }
    __syncthreads();

    if (wv == 0) {
        float s1 = 0.f, s2 = 0.f;
#pragma unroll
        for (int q = 0; q < 4; q++) { float vv = t5[lane + 64 * q]; s1 += vv; s2 += vv * vv; }
#pragma unroll
        for (int off = 32; off; off >>= 1) { s1 += __shfl_xor(s1, off); s2 += __shfl_xor(s2, off); }
        if (lane == 0) {
            float mu = s1 * (1.f / 256.f);
            float var = s2 * (1.f / 256.f) - mu * mu;
            stat[0] = mu; stat[1] = rsqrtf(var + EPSF);
        }
    }
    __syncthreads();
    t5buf[(size_t)b * 256 + tid] = t5[tid];
    z2_5[(size_t)b * 256 + tid] = (t5[tid] - stat[0]) * stat[1] * ln2_g[tid] + ln2_b[tid];
}

// ---------------------------------------------------------------------------
// ff1 + exact gelu: grid (128,4), quarter of 512 outputs per block.
// ---------------------------------------------------------------------------
__global__ __launch_bounds__(256) void ff1_gelu(
    const float* __restrict__ z2_5, const float* __restrict__ ff_w1,
    const float* __restrict__ ff_b1, float* __restrict__ f5)
{
    __shared__ float zsh[256];
    const int b = blockIdx.x, q = blockIdx.y, tid = threadIdx.x;
    const int g4 = tid >> 2, l4 = tid & 3;
    zsh[tid] = z2_5[(size_t)b * 256 + tid];
    __syncthreads();
    for (int tt = g4; tt < 128; tt += 64) {
        const int jj = q * 128 + tt;
        float a = 0.f;
#pragma unroll 8
        for (int j = 0; j < 64; j++) {
            int k = l4 + 4 * j;
            a += zsh[k] * ff_w1[(size_t)k * 512 + jj];
        }
        a += __shfl_xor(a, 1);
        a += __shfl_xor(a, 2);
        if (l4 == 0) {
            a += ff_b1[jj];
            f5[(size_t)b * 512 + jj] = 0.5f * a * (1.f + erff(a * 0.70710678118654752f));
        }
    }
}

// ---------------------------------------------------------------------------
// ff2 + residual: grid (128,2), half of 256 outputs per block -> t6.
// ---------------------------------------------------------------------------
__global__ __launch_bounds__(256) void ff2_half(
    const float* __restrict__ f5, const float* __restrict__ ff_w2,
    const float* __restrict__ ff_b2, const float* __restrict__ t5buf,
    float* __restrict__ t6)
{
    __shared__ float fsh[512];
    const int b = blockIdx.x, h = blockIdx.y, tid = threadIdx.x;
    const int g4 = tid >> 2, l4 = tid & 3;
    fsh[tid] = f5[(size_t)b * 512 + tid];
    fsh[tid + 256] = f5[(size_t)b * 512 + tid + 256];
    __syncthreads();
    for (int tt = g4; tt < 128; tt += 64) {
        const int o = h * 128 + tt;
        float a = 0.f;
#pragma unroll 8
        for (int j = 0; j < 128; j++) {
            int k = l4 + 4 * j;
            a += fsh[k] * ff_w2[(size_t)k * 256 + o];
        }
        a += __shfl_xor(a, 1);
        a += __shfl_xor(a, 2);
        if (l4 == 0)
            t6[(size_t)b * 256 + o] = a + ff_b2[o] + t5buf[(size_t)b * 256 + o];
    }
}

// ---------------------------------------------------------------------------
// fin GEMM with fused LNF: reads t6, computes per-row LNF stats in-block
// (redundant across x-blocks, deterministic), normalizes, then GEMM.
// ---------------------------------------------------------------------------
__global__ __launch_bounds__(256) void fin_gemm(const float* __restrict__ t6,
    const float* __restrict__ lnf_g, const float* __restrict__ lnf_b,
    const float* __restrict__ fin_w, const float* __restrict__ fin_b,
    float* __restrict__ refined5)
{
    __shared__ float tf[16][256];
    __shared__ float stat[16][2];
    int tid = threadIdx.x;
    int nb = blockIdx.x * 256 + tid;
    int bg = blockIdx.y * 16;
    for (int e = tid; e < 4096; e += 256)
        tf[e >> 8][e & 255] = t6[(size_t)(bg + (e >> 8)) * 256 + (e & 255)];
    __syncthreads();
    {
        int r = tid >> 4, sl = tid & 15;
        float s1 = 0.f, s2 = 0.f;
#pragma unroll
        for (int j = 0; j < 16; j++) {
            float vv = tf[r][sl + 16 * j];
            s1 += vv; s2 += vv * vv;
        }
#pragma unroll
        for (int off = 8; off; off >>= 1) { s1 += __shfl_xor(s1, off); s2 += __shfl_xor(s2, off); }
        if (sl == 0) {
            float mu = s1 * (1.f / 256.f);
            float var = s2 * (1.f / 256.f) - mu * mu;
            stat[r][0] = mu; stat[r][1] = rsqrtf(var + EPSF);
        }
    }
    __syncthreads();
    for (int e = tid; e < 4096; e += 256) {
        int r = e >> 8, c = e & 255;
        tf[r][c] = (tf[r][c] - stat[r][0]) * stat[r][1] * lnf_g[c] + lnf_b[c];
    }
    __syncthreads();
    if (nb < 5760) {
        float acc[16];
#pragma unroll
        for (int bb = 0; bb < 16; bb++) acc[bb] = 0.f;
        for (int k = 0; k < 256; k++) {
            float wv = fin_w[(size_t)k * 5760 + nb];
#pragma unroll
            for (int bb = 0; bb < 16; bb++) acc[bb] += tf[bb][k] * wv;
        }
        float fb = fin_b[nb];
#pragma unroll
        for (int bb = 0; bb < 16; bb++)
            refined5[(size_t)(bg + bb) * 5760 + nb] = acc[bb] + fb;
    }
}

// ---------------------------------------------------------------------------
extern "C" void kernel_launch(void* const* d_in, const int* in_sizes, int n_in,
                              void* d_out, int out_size, void* d_ws, size_t ws_size,
                              hipStream_t stream)
{
    const float* x      = (const float*)d_in[0];
    const float* ext_w1 = (const float*)d_in[1];
    const float* ext_b1 = (const float*)d_in[2];
    const float* ext_g  = (const float*)d_in[3];
    const float* ext_bb = (const float*)d_in[4];
    const float* ext_m  = (const float*)d_in[5];
    const float* ext_v  = (const float*)d_in[6];
    const float* ext_w2 = (const float*)d_in[7];
    const float* ext_b2 = (const float*)d_in[8];
    const float* cls_w1 = (const float*)d_in[9];
    const float* cls_b1 = (const float*)d_in[10];
    const float* cls_g  = (const float*)d_in[11];
    const float* cls_bb = (const float*)d_in[12];
    const float* cls_m  = (const float*)d_in[13];
    const float* cls_v  = (const float*)d_in[14];
    const float* cls_w2 = (const float*)d_in[15];
    const float* cls_b2 = (const float*)d_in[16];
    const float* tok_w  = (const float*)d_in[17];
    const float* tok_b  = (const float*)d_in[18];
    const float* emb    = (const float*)d_in[19];
    const float* ln1_g  = (const float*)d_in[20];
    const float* ln1_b  = (const float*)d_in[21];
    const float* qkv_w  = (const float*)d_in[22];
    const float* out_w  = (const float*)d_in[23];
    const float* out_b  = (const float*)d_in[24];
    const float* ln2_g  = (const float*)d_in[25];
    const float* ln2_b  = (const float*)d_in[26];
    const float* ff_w1  = (const float*)d_in[27];
    const float* ff_b1  = (const float*)d_in[28];
    const float* ff_w2  = (const float*)d_in[29];
    const float* ff_b2  = (const float*)d_in[30];
    const float* lnf_g  = (const float*)d_in[31];
    const float* lnf_b  = (const float*)d_in[32];
    const float* fin_w  = (const float*)d_in[33];
    const float* fin_b  = (const float*)d_in[34];

    float* out = (float*)d_out;
    float* ws  = (float*)d_ws;

    // workspace layout (float offsets)
    float*  Wc32     = ws;                        // 184320
    float*  cconst   = ws + 184320;               // 160
    ushort* Wchi     = (ushort*)(ws + 184480);    // 92160 floats
    ushort* Wclo     = (ushort*)(ws + 276640);    // 92160 floats
    float*  logitsP  = ws + 368800;               // 2*18432*160 = 5898240
    float*  partials = ws + 6267040;              // 4608
    float*  refined5 = ws + 6435488;              // 737280
    float*  tpart    = ws + 7172768;              // 262144
    int*    amax     = (int*)(ws + 7434912);      // 18432
    int*    flag     = (int*)(ws + 7453344);      // 1
    int*    cand_cnt = (int*)(ws + 7453345);      // 1
    int*    cand_lst = (int*)(ws + 7453346);      // 18432
    float*  w1cT     = ws + 7471780;              // 294912
    float*  w2cT     = ws + 7766692;              // 36864
    float*  WcT      = ws + 7803556;              // 184320
    float*  sbuf     = ws + 8184484;              // 32768
    float*  qkbuf    = ws + 8217252;              // 147456
    float*  z2_5     = ws + 8364708;              // 32768
    float*  t5buf    = ws + 8397476;              // 32768
    float*  f5buf    = ws + 8430244;              // 65536
    float*  t6buf    = ws + 8495780;              // 32768 -> ends 8528548

    // output offsets: ext | cls | ext2 | cls2
    float* out_ext  = out;
    float* out_cls  = out + 36864;
    float* out_ext2 = out + 2691072;
    float* out_cls2 = out + 2727936;

    dim3 blk(256);

    // weight prep (independent of x); also zeroes cand_cnt
    wcomb_build<<<dim3(160, 4), blk, 0, stream>>>(
        ext_w1, ext_b1, ext_g, ext_bb, ext_m, ext_v, ext_w2, ext_b2,
        cls_w1, cls_b1, cls_g, cls_bb, cls_m, cls_v, cls_w2, cls_b2,
        Wc32, Wchi, Wclo, cconst, cand_cnt);
    transpose3<<<dim3(36, 8, 3), blk, 0, stream>>>(cls_w1, w1cT, cls_w2, w2cT, Wc32, WcT);

    // pass 1
    logits_gemm<<<dim3(288, NKS), dim3(512), 0, stream>>>(x, Wchi, Wclo, logitsP);
    softmax_heads<0><<<4608, blk, 0, stream>>>(logitsP, cconst, out_cls, out_ext, amax, partials,
        cand_cnt, cand_lst, nullptr, nullptr, nullptr, nullptr);
    reduce_flag<<<1, blk, 0, stream>>>(partials, 4608, flag);
    fixup_list<<<256, blk, 0, stream>>>(cand_cnt, cand_lst, x,
        w1cT, cls_b1, cls_g, cls_bb, cls_m, cls_v, w2cT, cls_b2, amax);

    // refine chain (always computed; application predicated on flag)
    tok_partial<<<dim3(128, 8), blk, 0, stream>>>(x, amax, tok_w, tpart);
    qkv_gemm<<<dim3(128, 7), blk, 0, stream>>>(tpart, tok_b, emb, ln1_g, ln1_b, qkv_w,
        qkbuf, sbuf);
    attn_out<<<128, blk, 0, stream>>>(qkbuf, sbuf, emb, out_w, out_b, ln2_g, ln2_b, z2_5, t5buf);
    ff1_gelu<<<dim3(128, 4), blk, 0, stream>>>(z2_5, ff_w1, ff_b1, f5buf);
    ff2_half<<<dim3(128, 2), blk, 0, stream>>>(f5buf, ff_w2, ff_b2, t5buf, t6buf);
    fin_gemm<<<dim3(23, 8), blk, 0, stream>>>(t6buf, lnf_g, lnf_b, fin_w, fin_b, refined5);

    // pass 2 = pass 1 logits + rank-40 delta fused into softmax
    softmax_heads<1><<<4608, blk, 0, stream>>>(logitsP, cconst, out_cls2, out_ext2, amax, nullptr,
        nullptr, nullptr, x, WcT, refined5, flag);
}

// Round 20
// 262.063 us; speedup vs baseline: 1.0185x; 1.0185x over previous
//
#include <hip/hip_runtime.h>
#include <math.h>

#define EPSF 1e-5f
#define GAPTH 2e-4f     // MFMA logit err ~3e-6; 30-70x margin (0 flips observed)
#define NKS 2           // K-split slices for logits GEMM (576 each)
#define KSL 576
#define RROWS 18432
#define LPAD 44         // LDS row pad: 44 ushorts = 22 banks -> row-starts distinct mod 32

// B=128, C=8, H=144, W=144, CW=1152, R=18432, TW=5, OG=2, NCLS=6, DT=256, ITC=5760
// Collapsed head: logits[row, j] = sum_k Wc[j,k] * x'[row,k] + cconst[j]
// Pass 2 = pass 1 + rank-40 per-row delta, fused into softmax (DELTA=1).

typedef __attribute__((ext_vector_type(8))) short short8v;
typedef __attribute__((ext_vector_type(4))) float f32x4;
typedef unsigned short ushort;
typedef unsigned int uint;

__device__ inline ushort f2bf(float f) {
    uint u = __float_as_uint(f);
    uint r = (u + 0x7FFFu + ((u >> 16) & 1u)) >> 16;
    return (ushort)r;
}
__device__ inline float bf2f(ushort h) { return __uint_as_float(((uint)h) << 16); }

// ---------------------------------------------------------------------------
// Build combined weights, K-split over blockIdx.y; ILP-4 o-loop.
// Also zeroes cand_count (folded zero_counters dispatch).
// ---------------------------------------------------------------------------
__global__ __launch_bounds__(256) void wcomb_build(
    const float* __restrict__ w1e, const float* __restrict__ b1e, const float* __restrict__ ge,
    const float* __restrict__ bbe, const float* __restrict__ me, const float* __restrict__ ve,
    const float* __restrict__ w2e, const float* __restrict__ b2e,
    const float* __restrict__ w1c, const float* __restrict__ b1c, const float* __restrict__ gc,
    const float* __restrict__ bbc, const float* __restrict__ mc, const float* __restrict__ vc,
    const float* __restrict__ w2c, const float* __restrict__ b2c,
    float* __restrict__ Wc32, ushort* __restrict__ Wchi, ushort* __restrict__ Wclo,
    float* __restrict__ cconst, int* __restrict__ cand_count)
{
    __shared__ float coef[256];
    __shared__ float csum[4];
    const int j = blockIdx.x, kq = blockIdx.y, tid = threadIdx.x;
    const int lane = tid & 63, wid = tid >> 6;

    if (j == 0 && kq == 0 && tid == 0) *cand_count = 0;

    const float *w1 = nullptr, *w2row = nullptr, *b1 = nullptr, *g = nullptr,
                *bb = nullptr, *m = nullptr, *v = nullptr;
    float b2v = 0.f;
    int valid = 0;
    if (j < 144) {
        valid = 1; w1 = w1c; w2row = w2c + (size_t)j * 256;
        b1 = b1c; g = gc; bb = bbc; m = mc; v = vc; b2v = b2c[j];
    } else if (j < 146) {
        valid = 1; w1 = w1e; w2row = w2e + (size_t)(j - 144) * 256;
        b1 = b1e; g = ge; bb = bbe; m = me; v = ve; b2v = b2e[j - 144];
    }

    float cf = 0.f, cc = 0.f;
    if (valid) {
        float s = g[tid] * rsqrtf(v[tid] + EPSF);
        float w2v = w2row[tid];
        cf = w2v * s;
        cc = w2v * ((b1[tid] - m[tid]) * s + bb[tid]);
    }
    coef[tid] = cf;
    if (kq == 0) {
        float t = cc;
#pragma unroll
        for (int off = 32; off; off >>= 1) t += __shfl_xor(t, off);
        if (lane == 0) csum[wid] = t;
    }
    __syncthreads();
    if (kq == 0 && tid == 0)
        cconst[j] = valid ? ((csum[0] + csum[1]) + (csum[2] + csum[3]) + b2v) : 0.f;

    for (int k = kq * 288 + tid; k < (kq + 1) * 288; k += 256) {
        float acc = 0.f;
        if (valid) {
            float a0 = 0.f, a1 = 0.f, a2 = 0.f, a3 = 0.f;
            for (int o = 0; o < 256; o += 4) {
                a0 += coef[o]     * w1[(size_t)o * 1152 + k];
                a1 += coef[o + 1] * w1[(size_t)(o + 1) * 1152 + k];
                a2 += coef[o + 2] * w1[(size_t)(o + 2) * 1152 + k];
                a3 += coef[o + 3] * w1[(size_t)(o + 3) * 1152 + k];
            }
            acc = (a0 + a1) + (a2 + a3);
        }
        Wc32[(size_t)j * 1152 + k] = acc;
        ushort hi = f2bf(acc);
        Wchi[(size_t)j * 1152 + k] = hi;
        Wclo[(size_t)j * 1152 + k] = f2bf(acc - bf2f(hi));
    }
}

// ---------------------------------------------------------------------------
// three tiled transposes in one launch (blockIdx.z selects)
// ---------------------------------------------------------------------------
__global__ __launch_bounds__(256) void transpose3(
    const float* __restrict__ s0, float* __restrict__ d0,
    const float* __restrict__ s1, float* __restrict__ d1,
    const float* __restrict__ s2, float* __restrict__ d2)
{
    const float* src; float* dst; int R, Cc;
    if (blockIdx.z == 0)      { src = s0; dst = d0; R = 256; Cc = 1152; }
    else if (blockIdx.z == 1) { src = s1; dst = d1; R = 144; Cc = 256;
                                if (blockIdx.x >= 8 || blockIdx.y >= 5) return; }
    else                      { src = s2; dst = d2; R = 160; Cc = 1152;
                                if (blockIdx.y >= 5) return; }
    __shared__ float tile[32][33];
    const int rb = blockIdx.y * 32, cb = blockIdx.x * 32;
    const int tx = threadIdx.x & 31, ty = threadIdx.x >> 5;
#pragma unroll
    for (int i = ty; i < 32; i += 8) {
        int r = rb + i, c = cb + tx;
        tile[i][tx] = (r < R && c < Cc) ? src[(size_t)r * Cc + c] : 0.f;
    }
    __syncthreads();
#pragma unroll
    for (int i = ty; i < 32; i += 8) {
        int c = cb + i, r = rb + tx;
        if (c < Cc && r < R) dst[(size_t)c * R + r] = tile[tx][i];
    }
}

// ---------------------------------------------------------------------------
// logits GEMM: M=18432, N=160(146 used), K=1152 in NKS=2 slices of 576.
// BM=64, BN=160, BK=32; 4 waves as 2m x 2n; wave tile 32x80 (2x5 frags).
// LOAD(t+1) after barrier1 overlaps the MFMA section.
// LDS rows padded to 44 ushorts (22 banks): row-starts (22r)%32 distinct for
// r=0..15 -> fragment ds_read_b128 conflict-free (was 20 banks, period-8).
// ---------------------------------------------------------------------------
__global__ __launch_bounds__(256) void logits_gemm(
    const float* __restrict__ x, const ushort* __restrict__ Wchi, const ushort* __restrict__ Wclo,
    float* __restrict__ logits_part)
{
    __shared__ ushort Ahi[64][LPAD], Alo[64][LPAD], Bhi[160][LPAD], Blo[160][LPAD];
    const int tid = threadIdx.x;
    const int lane = tid & 63, wid = tid >> 6;
    const int wm = wid & 1, wn = wid >> 1;
    const int rb = blockIdx.x * 64;
    const int ks = blockIdx.y;
    const int kbase = ks * KSL;
    const int NIT = KSL / 32;                    // 18

    const int rl = tid >> 2, kk = (tid & 3) << 3;
    const int arow = rb + rl;
    const int ab = arow / 144, ahh = arow - ab * 144;

    const int br0 = tid >> 2, bk0 = (tid & 3) << 3;
    const int br2 = 128 + (tid >> 2), bk2 = (tid & 3) << 3;

    float av[8];
    short8v vbh0, vbl0, vbh1, vbl1, vbh2, vbl2;

    auto LOAD = [&](int kb) {
        int k1 = kb + kk, c1 = k1 / 144, w1 = k1 - c1 * 144;
        const float4 t0 = *reinterpret_cast<const float4*>(
            x + (((size_t)(ab * 8 + c1) * 144 + ahh) * 144 + w1));
        const float4 t1 = *reinterpret_cast<const float4*>(
            x + (((size_t)(ab * 8 + c1) * 144 + ahh) * 144 + w1 + 4));
        av[0] = t0.x; av[1] = t0.y; av[2] = t0.z; av[3] = t0.w;
        av[4] = t1.x; av[5] = t1.y; av[6] = t1.z; av[7] = t1.w;
        size_t o0 = (size_t)br0 * 1152 + kb + bk0;
        vbh0 = *reinterpret_cast<const short8v*>(Wchi + o0);
        vbl0 = *reinterpret_cast<const short8v*>(Wclo + o0);
        size_t o1 = (size_t)(br0 + 64) * 1152 + kb + bk0;
        vbh1 = *reinterpret_cast<const short8v*>(Wchi + o1);
        vbl1 = *reinterpret_cast<const short8v*>(Wclo + o1);
        if (tid < 128) {
            size_t o2 = (size_t)br2 * 1152 + kb + bk2;
            vbh2 = *reinterpret_cast<const short8v*>(Wchi + o2);
            vbl2 = *reinterpret_cast<const short8v*>(Wclo + o2);
        }
    };

    auto STORE = [&]() {
        short8v hv, lv;
#pragma unroll
        for (int q = 0; q < 8; q++) {
            ushort h = f2bf(av[q]);
            hv[q] = (short)h;
            lv[q] = (short)f2bf(av[q] - bf2f(h));
        }
        *reinterpret_cast<short8v*>(&Ahi[rl][kk]) = hv;
        *reinterpret_cast<short8v*>(&Alo[rl][kk]) = lv;
        *reinterpret_cast<short8v*>(&Bhi[br0][bk0]) = vbh0;
        *reinterpret_cast<short8v*>(&Blo[br0][bk0]) = vbl0;
        *reinterpret_cast<short8v*>(&Bhi[br0 + 64][bk0]) = vbh1;
        *reinterpret_cast<short8v*>(&Blo[br0 + 64][bk0]) = vbl1;
        if (tid < 128) {
            *reinterpret_cast<short8v*>(&Bhi[br2][bk2]) = vbh2;
            *reinterpret_cast<short8v*>(&Blo[br2][bk2]) = vbl2;
        }
    };

    f32x4 acc[2][5];
#pragma unroll
    for (int mt = 0; mt < 2; mt++)
#pragma unroll
        for (int nt = 0; nt < 5; nt++) acc[mt][nt] = (f32x4){0.f, 0.f, 0.f, 0.f};

    const int fr = lane & 15, fg = (lane >> 4) << 3;

    LOAD(kbase);
    for (int t = 0; t < NIT; t++) {
        STORE();
        __syncthreads();
        if (t < NIT - 1) LOAD(kbase + (t + 1) * 32);   // overlaps MFMA below
        short8v ah0 = *reinterpret_cast<const short8v*>(&Ahi[wm * 32 + fr][fg]);
        short8v al0 = *reinterpret_cast<const short8v*>(&Alo[wm * 32 + fr][fg]);
        short8v ah1 = *reinterpret_cast<const short8v*>(&Ahi[wm * 32 + 16 + fr][fg]);
        short8v al1 = *reinterpret_cast<const short8v*>(&Alo[wm * 32 + 16 + fr][fg]);
#pragma unroll
        for (int nt = 0; nt < 5; nt++) {
            short8v bh = *reinterpret_cast<const short8v*>(&Bhi[wn * 80 + nt * 16 + fr][fg]);
            short8v bl = *reinterpret_cast<const short8v*>(&Blo[wn * 80 + nt * 16 + fr][fg]);
            acc[0][nt] = __builtin_amdgcn_mfma_f32_16x16x32_bf16(ah0, bh, acc[0][nt], 0, 0, 0);
            acc[0][nt] = __builtin_amdgcn_mfma_f32_16x16x32_bf16(ah0, bl, acc[0][nt], 0, 0, 0);
            acc[0][nt] = __builtin_amdgcn_mfma_f32_16x16x32_bf16(al0, bh, acc[0][nt], 0, 0, 0);
            acc[1][nt] = __builtin_amdgcn_mfma_f32_16x16x32_bf16(ah1, bh, acc[1][nt], 0, 0, 0);
            acc[1][nt] = __builtin_amdgcn_mfma_f32_16x16x32_bf16(ah1, bl, acc[1][nt], 0, 0, 0);
            acc[1][nt] = __builtin_amdgcn_mfma_f32_16x16x32_bf16(al1, bh, acc[1][nt], 0, 0, 0);
        }
        __syncthreads();
    }

    float* base = logits_part + (size_t)ks * RROWS * 160;
#pragma unroll
    for (int mt = 0; mt < 2; mt++) {
#pragma unroll
        for (int nt = 0; nt < 5; nt++) {
            int gcol = wn * 80 + nt * 16 + fr;
            if (gcol < 146) {
                float* dst = base + (size_t)(rb + wm * 32 + mt * 16 + ((lane >> 4) << 2)) * 160 + gcol;
#pragma unroll
                for (int i = 0; i < 4; i++)
                    dst[(size_t)i * 160] = acc[mt][nt][i];
            }
        }
    }
}

// ---------------------------------------------------------------------------
// merged softmax over summed K-slices; DELTA=1 adds rank-40 per-row patch delta.
// ---------------------------------------------------------------------------
template<int DELTA>
__global__ __launch_bounds__(256) void softmax_heads(
    const float* __restrict__ logits_part, const float* __restrict__ cconst,
    float* __restrict__ out_cls, float* __restrict__ out_ext,
    int* __restrict__ amax, float* __restrict__ partials,
    int* __restrict__ cand_count, int* __restrict__ cand_list,
    const float* __restrict__ x, const float* __restrict__ WcT,
    const float* __restrict__ refined5, const int* __restrict__ flag)
{
    __shared__ float ps[4];
    __shared__ float dL[4][148];
    __shared__ float dsh[4][40];
    __shared__ int   ksh[4][40];
    const int r4 = threadIdx.x >> 6, lane = threadIdx.x & 63;
    const int row = blockIdx.x * 4 + r4;

    if (DELTA) {
        const int fl = *flag;
        if (fl) {
            const int b = row / 144, hh = row - b * 144;
            const int a = amax[row];
            if (lane < 40) {
                int c = lane / 5, tw = lane - c * 5;
                int w = a - 2 + tw;
                float d = 0.f; int k = 0;
                if (w >= 0 && w < 144) {
                    k = c * 144 + w;
                    d = refined5[(size_t)b * 5760 + (c * 144 + hh) * 5 + tw]
                      - x[((size_t)(b * 8 + c) * 144 + hh) * 144 + w];
                }
                dsh[r4][lane] = d; ksh[r4][lane] = k;
            }
            __syncthreads();
#pragma unroll
            for (int rj = 0; rj < 3; rj++) {
                int j = lane + rj * 64;
                if (j < 146) {
                    float acc = 0.f;
#pragma unroll 8
                    for (int i = 0; i < 40; i++)
                        acc += WcT[(size_t)ksh[r4][i] * 160 + j] * dsh[r4][i];
                    dL[r4][j] = acc;
                }
            }
        } else {
#pragma unroll
            for (int rj = 0; rj < 3; rj++) {
                int j = lane + rj * 64;
                if (j < 146) dL[r4][j] = 0.f;
            }
        }
        __syncthreads();
    }

    const float* L0 = logits_part + (size_t)row * 160;
    const float* L1 = L0 + (size_t)RROWS * 160;
    float v0 = L0[lane] + L1[lane] + cconst[lane];
    float v1 = L0[lane + 64] + L1[lane + 64] + cconst[lane + 64];
    float v2 = (lane < 16) ? (L0[lane + 128] + L1[lane + 128] + cconst[lane + 128])
                           : -3.0e38f;
    if (DELTA) {
        v0 += dL[r4][lane];
        v1 += dL[r4][lane + 64];
        if (lane < 16) v2 += dL[r4][lane + 128];
    }
    float m = v0; int mi = lane;
    if (v1 > m) { m = v1; mi = lane + 64; }
    if (v2 > m) { m = v2; mi = lane + 128; }
    float m1 = v0, m2 = -3.0e38f;
    if (v1 > m1) { m2 = m1; m1 = v1; } else m2 = v1;
    if (v2 > m1) { m2 = m1; m1 = v2; } else m2 = fmaxf(m2, v2);
#pragma unroll
    for (int off = 32; off; off >>= 1) {
        float om = __shfl_xor(m, off);
        int   oi = __shfl_xor(mi, off);
        if (om > m || (om == m && oi < mi)) { m = om; mi = oi; }
        float om1 = __shfl_xor(m1, off);
        float om2 = __shfl_xor(m2, off);
        float nm1 = fmaxf(m1, om1);
        m2 = fmaxf(fminf(m1, om1), fmaxf(m2, om2));
        m1 = nm1;
    }
    float e0 = expf(v0 - m), e1 = expf(v1 - m);
    float e2 = (lane < 16) ? expf(v2 - m) : 0.f;
    float s = e0 + e1 + e2;
#pragma unroll
    for (int off = 32; off; off >>= 1) s += __shfl_xor(s, off);
    float inv = 1.f / s;
    float* O = out_cls + (size_t)row * 144;
    O[lane] = e0 * inv;
    O[lane + 64] = e1 * inv;
    if (lane < 16) O[lane + 128] = e2 * inv;

    float l0 = L0[144] + L1[144] + cconst[144];
    float l1 = L0[145] + L1[145] + cconst[145];
    if (DELTA) { l0 += dL[r4][144]; l1 += dL[r4][145]; }
    float mx = fmaxf(l0, l1);
    float ee0 = expf(l0 - mx), ee1 = expf(l1 - mx);
    float einv = 1.f / (ee0 + ee1);
    float p0 = ee0 * einv;
    if (lane == 0) {
        out_ext[(size_t)row * 2] = p0;
        out_ext[(size_t)row * 2 + 1] = ee1 * einv;
        if (amax != nullptr && !DELTA) {
            amax[row] = mi;
            if (m1 - m2 < GAPTH) {
                int slot = atomicAdd(cand_count, 1);
                cand_list[slot] = row;
            }
        }
    }
    if (partials != nullptr) {
        if (lane == 0) ps[r4] = p0;
        __syncthreads();
        if (threadIdx.x == 0) partials[blockIdx.x] = (ps[0] + ps[1]) + (ps[2] + ps[3]);
    }
}

__global__ __launch_bounds__(256) void reduce_flag(const float* __restrict__ partials, int n,
                                                   int* __restrict__ flag)
{
    __shared__ float sm[256];
    int tid = threadIdx.x;
    float s = 0.f;
    for (int i = tid; i < n; i += 256) s += partials[i];
    sm[tid] = s; __syncthreads();
    for (int off = 128; off; off >>= 1) {
        if (tid < off) sm[tid] += sm[tid + off];
        __syncthreads();
    }
    if (tid == 0) *flag = (sm[0] * (1.f / 18432.f) > 0.3f) ? 1 : 0;
}

// ---------------------------------------------------------------------------
// fixup over compacted candidate list: exact f32 two-stage recompute of argmax.
// ---------------------------------------------------------------------------
__global__ __launch_bounds__(256) void fixup_list(
    const int* __restrict__ cand_count, const int* __restrict__ cand_list,
    const float* __restrict__ x,
    const float* __restrict__ w1cT, const float* __restrict__ b1c,
    const float* __restrict__ gc, const float* __restrict__ bbc,
    const float* __restrict__ mc, const float* __restrict__ vc,
    const float* __restrict__ w2cT, const float* __restrict__ b2c,
    int* __restrict__ amax)
{
    __shared__ float xrow[1152];
    __shared__ float hsh[256];
    __shared__ float Lsh[144];
    const int tid = threadIdx.x;
    const int n = *cand_count;

    for (int ci = blockIdx.x; ci < n; ci += gridDim.x) {
        const int row = cand_list[ci];
        const int b = row / 144, hh = row - b * 144;
        for (int e = tid; e < 1152; e += 256) {
            int c = e / 144, w = e - c * 144;
            xrow[e] = x[(((size_t)(b * 8 + c) * 144 + hh) * 144) + w];
        }
        __syncthreads();
        {
            float a0 = 0.f, a1 = 0.f, a2 = 0.f, a3 = 0.f;
#pragma unroll 4
            for (int k = 0; k < 1152; k += 4) {
                a0 += w1cT[(size_t)k * 256 + tid] * xrow[k];
                a1 += w1cT[(size_t)(k + 1) * 256 + tid] * xrow[k + 1];
                a2 += w1cT[(size_t)(k + 2) * 256 + tid] * xrow[k + 2];
                a3 += w1cT[(size_t)(k + 3) * 256 + tid] * xrow[k + 3];
            }
            float a = (a0 + a1) + (a2 + a3);
            float sc = gc[tid] * rsqrtf(vc[tid] + EPSF);
            hsh[tid] = (a + b1c[tid] - mc[tid]) * sc + bbc[tid];
        }
        __syncthreads();
        if (tid < 144) {
            float a0 = 0.f, a1 = 0.f, a2 = 0.f, a3 = 0.f;
#pragma unroll 4
            for (int k = 0; k < 256; k += 4) {
                a0 += w2cT[(size_t)k * 144 + tid] * hsh[k];
                a1 += w2cT[(size_t)(k + 1) * 144 + tid] * hsh[k + 1];
                a2 += w2cT[(size_t)(k + 2) * 144 + tid] * hsh[k + 2];
                a3 += w2cT[(size_t)(k + 3) * 144 + tid] * hsh[k + 3];
            }
            Lsh[tid] = (a0 + a1) + (a2 + a3) + b2c[tid];
        }
        __syncthreads();
        if (tid == 0) {
            int bi = 0; float bv = Lsh[0];
            for (int j = 1; j < 144; j++) if (Lsh[j] > bv) { bv = Lsh[j]; bi = j; }
            amax[row] = bi;
        }
        __syncthreads();
    }
}

// ---------------------------------------------------------------------------
// tok GEMM with fused patch gather; 4 accumulators for ILP.
// ---------------------------------------------------------------------------
__global__ __launch_bounds__(256) void tok_partial(const float* __restrict__ x,
    const int* __restrict__ amax, const float* __restrict__ tok_w, float* __restrict__ tpart)
{
    __shared__ float P[720];
    __shared__ int ash[144];
    int b = blockIdx.x, c = blockIdx.y, tid = threadIdx.x;
    if (tid < 144) ash[tid] = amax[b * 144 + tid];
    __syncthreads();
    for (int e = tid; e < 720; e += 256) {
        int hh = e / 5, tw = e - hh * 5;
        int w = ash[hh] + tw - 2;
        P[e] = (w >= 0 && w < 144) ? x[(((size_t)(b * 8 + c) * 144 + hh) * 144) + w] : 0.f;
    }
    __syncthreads();
    const float* wbase = tok_w + (size_t)c * 720 * 256;
    float a0 = 0.f, a1 = 0.f, a2 = 0.f, a3 = 0.f;
    for (int k = 0; k < 720; k += 4) {
        a0 += P[k]     * wbase[(size_t)k * 256 + tid];
        a1 += P[k + 1] * wbase[(size_t)(k + 1) * 256 + tid];
        a2 += P[k + 2] * wbase[(size_t)(k + 2) * 256 + tid];
        a3 += P[k + 3] * wbase[(size_t)(k + 3) * 256 + tid];
    }
    tpart[((size_t)b * 8 + c) * 256 + tid] = (a0 + a1) + (a2 + a3);
}

// ---------------------------------------------------------------------------
// qkv_gemm (fused prep): grid (128,7). Each block sums tpart -> token base s,
// does LN1 for its token in-LDS, then its qkv slice. y<6: k/v cols 64..191
// for token y; y==6: q cols 0..63 for token 5 (also writes sbuf).
// ---------------------------------------------------------------------------
__global__ __launch_bounds__(256) void qkv_gemm(
    const float* __restrict__ tpart, const float* __restrict__ tok_b,
    const float* __restrict__ emb,
    const float* __restrict__ ln1_g, const float* __restrict__ ln1_b,
    const float* __restrict__ qkv_w,
    float* __restrict__ qkbuf, float* __restrict__ sbuf)
{
    __shared__ float zrow[256];
    __shared__ float r8[8];
    const int b = blockIdx.x, y = blockIdx.y, tid = threadIdx.x;
    const int i = (y < 6) ? y : 5;
    const int lane = tid & 63, wv = tid >> 6;
    const int g4 = tid >> 2, l4 = tid & 3;

    float a = tok_b[tid];
#pragma unroll
    for (int ks = 0; ks < 8; ks++) a += tpart[((size_t)b * 8 + ks) * 256 + tid];
    if (y == 6) sbuf[(size_t)b * 256 + tid] = a;

    float v = a + emb[i * 256 + tid];
    float s1 = v, s2 = v * v;
#pragma unroll
    for (int off = 32; off; off >>= 1) { s1 += __shfl_down(s1, off); s2 += __shfl_down(s2, off); }
    if (lane == 0) { r8[wv * 2] = s1; r8[wv * 2 + 1] = s2; }
    __syncthreads();
    float t1 = (r8[0] + r8[2]) + (r8[4] + r8[6]);
    float t2 = (r8[1] + r8[3]) + (r8[5] + r8[7]);
    float mu = t1 * (1.f / 256.f);
    float var = t2 * (1.f / 256.f) - mu * mu;
    zrow[tid] = (v - mu) * rsqrtf(var + EPSF) * ln1_g[tid] + ln1_b[tid];
    __syncthreads();

    if (y < 6) {
        for (int tt = g4; tt < 128; tt += 64) {
            const int c = 64 + tt;
            float acc = 0.f;
#pragma unroll 8
            for (int j = 0; j < 64; j++) {
                int k = l4 + 4 * j;
                acc += zrow[k] * qkv_w[(size_t)k * 192 + c];
            }
            acc += __shfl_xor(acc, 1);
            acc += __shfl_xor(acc, 2);
            if (l4 == 0) qkbuf[((size_t)b * 6 + i) * 192 + c] = acc;
        }
    } else {
        const int c = g4;   // 0..63
        float acc = 0.f;
#pragma unroll 8
        for (int j = 0; j < 64; j++) {
            int k = l4 + 4 * j;
            acc += zrow[k] * qkv_w[(size_t)k * 192 + c];
        }
        acc += __shfl_xor(acc, 1);
        acc += __shfl_xor(acc, 2);
        if (l4 == 0) qkbuf[((size_t)b * 6 + 5) * 192 + c] = acc;
    }
}

// ---------------------------------------------------------------------------
// attn_out: attention row 5 + out-proj + residual + LN2 -> z2_5, t5buf.
// ---------------------------------------------------------------------------
__global__ __launch_bounds__(256) void attn_out(
    const float* __restrict__ qkbuf, const float* __restrict__ sbuf,
    const float* __restrict__ emb,
    const float* __restrict__ out_w, const float* __restrict__ out_b,
    const float* __restrict__ ln2_g, const float* __restrict__ ln2_b,
    float* __restrict__ z2_5, float* __restrict__ t5buf)
{
    __shared__ float qk[6][192];
    __shared__ float att[2][6];
    __shared__ float o5[64];
    __shared__ float t5[256];
    __shared__ float stat[2];
    const int b = blockIdx.x, tid = threadIdx.x;
    const int lane = tid & 63, wv = tid >> 6;
    const int g4 = tid >> 2, l4 = tid & 3;

    for (int e = tid; e < 1152; e += 256)
        qk[e / 192][e - (e / 192) * 192] = qkbuf[(size_t)b * 1152 + e];
    __syncthreads();

    if (tid < 12) {
        int h = tid / 6, j = tid - h * 6;
        float a = 0.f;
#pragma unroll
        for (int d = 0; d < 32; d++) a += qk[5][h * 32 + d] * qk[j][64 + h * 32 + d];
        att[h][j] = a * 0.17677669529663687f;
    }
    __syncthreads();
    if (tid < 2) {
        float m = -3.0e38f;
        for (int j = 0; j < 6; j++) m = fmaxf(m, att[tid][j]);
        float ssum = 0.f;
        for (int j = 0; j < 6; j++) { float e = expf(att[tid][j] - m); att[tid][j] = e; ssum += e; }
        float inv = 1.f / ssum;
        for (int j = 0; j < 6; j++) att[tid][j] *= inv;
    }
    __syncthreads();
    if (tid < 64) {
        int h = tid >> 5;
        float a = 0.f;
#pragma unroll
        for (int j = 0; j < 6; j++) a += att[h][j] * qk[j][128 + tid];
        o5[tid] = a;
    }
    __syncthreads();

    for (int tt = g4; tt < 256; tt += 64) {
        float a = 0.f;
#pragma unroll
        for (int j = 0; j < 16; j++) {
            int d = l4 + 4 * j;
            a += o5[d] * out_w[(size_t)d * 256 + tt];
        }
        a += __shfl_xor(a, 1);
        a += __shfl_xor(a, 2);
        if (l4 == 0)
            t5[tt] = a + out_b[tt] + sbuf[(size_t)b * 256 + tt] + emb[5 * 256 + tt];
    }
    __syncthreads();

    if (wv == 0) {
        float s1 = 0.f, s2 = 0.f;
#pragma unroll
        for (int q = 0; q < 4; q++) { float vv = t5[lane + 64 * q]; s1 += vv; s2 += vv * vv; }
#pragma unroll
        for (int off = 32; off; off >>= 1) { s1 += __shfl_xor(s1, off); s2 += __shfl_xor(s2, off); }
        if (lane == 0) {
            float mu = s1 * (1.f / 256.f);
            float var = s2 * (1.f / 256.f) - mu * mu;
            stat[0] = mu; stat[1] = rsqrtf(var + EPSF);
        }
    }
    __syncthreads();
    t5buf[(size_t)b * 256 + tid] = t5[tid];
    z2_5[(size_t)b * 256 + tid] = (t5[tid] - stat[0]) * stat[1] * ln2_g[tid] + ln2_b[tid];
}

// ---------------------------------------------------------------------------
// ff1 + exact gelu: grid (128,4), quarter of 512 outputs per block.
// ---------------------------------------------------------------------------
__global__ __launch_bounds__(256) void ff1_gelu(
    const float* __restrict__ z2_5, const float* __restrict__ ff_w1,
    const float* __restrict__ ff_b1, float* __restrict__ f5)
{
    __shared__ float zsh[256];
    const int b = blockIdx.x, q = blockIdx.y, tid = threadIdx.x;
    const int g4 = tid >> 2, l4 = tid & 3;
    zsh[tid] = z2_5[(size_t)b * 256 + tid];
    __syncthreads();
    for (int tt = g4; tt < 128; tt += 64) {
        const int jj = q * 128 + tt;
        float a = 0.f;
#pragma unroll 8
        for (int j = 0; j < 64; j++) {
            int k = l4 + 4 * j;
            a += zsh[k] * ff_w1[(size_t)k * 512 + jj];
        }
        a += __shfl_xor(a, 1);
        a += __shfl_xor(a, 2);
        if (l4 == 0) {
            a += ff_b1[jj];
            f5[(size_t)b * 512 + jj] = 0.5f * a * (1.f + erff(a * 0.70710678118654752f));
        }
    }
}

// ---------------------------------------------------------------------------
// ff2 + residual: grid (128,2), half of 256 outputs per block -> t6.
// ---------------------------------------------------------------------------
__global__ __launch_bounds__(256) void ff2_half(
    const float* __restrict__ f5, const float* __restrict__ ff_w2,
    const float* __restrict__ ff_b2, const float* __restrict__ t5buf,
    float* __restrict__ t6)
{
    __shared__ float fsh[512];
    const int b = blockIdx.x, h = blockIdx.y, tid = threadIdx.x;
    const int g4 = tid >> 2, l4 = tid & 3;
    fsh[tid] = f5[(size_t)b * 512 + tid];
    fsh[tid + 256] = f5[(size_t)b * 512 + tid + 256];
    __syncthreads();
    for (int tt = g4; tt < 128; tt += 64) {
        const int o = h * 128 + tt;
        float a = 0.f;
#pragma unroll 8
        for (int j = 0; j < 128; j++) {
            int k = l4 + 4 * j;
            a += fsh[k] * ff_w2[(size_t)k * 256 + o];
        }
        a += __shfl_xor(a, 1);
        a += __shfl_xor(a, 2);
        if (l4 == 0)
            t6[(size_t)b * 256 + o] = a + ff_b2[o] + t5buf[(size_t)b * 256 + o];
    }
}

// ---------------------------------------------------------------------------
// fin GEMM with fused LNF: reads t6, computes per-row LNF stats in-block
// (redundant across x-blocks, deterministic), normalizes, then GEMM.
// ---------------------------------------------------------------------------
__global__ __launch_bounds__(256) void fin_gemm(const float* __restrict__ t6,
    const float* __restrict__ lnf_g, const float* __restrict__ lnf_b,
    const float* __restrict__ fin_w, const float* __restrict__ fin_b,
    float* __restrict__ refined5)
{
    __shared__ float tf[16][256];
    __shared__ float stat[16][2];
    int tid = threadIdx.x;
    int nb = blockIdx.x * 256 + tid;
    int bg = blockIdx.y * 16;
    for (int e = tid; e < 4096; e += 256)
        tf[e >> 8][e & 255] = t6[(size_t)(bg + (e >> 8)) * 256 + (e & 255)];
    __syncthreads();
    {
        int r = tid >> 4, sl = tid & 15;
        float s1 = 0.f, s2 = 0.f;
#pragma unroll
        for (int j = 0; j < 16; j++) {
            float vv = tf[r][sl + 16 * j];
            s1 += vv; s2 += vv * vv;
        }
#pragma unroll
        for (int off = 8; off; off >>= 1) { s1 += __shfl_xor(s1, off); s2 += __shfl_xor(s2, off); }
        if (sl == 0) {
            float mu = s1 * (1.f / 256.f);
            float var = s2 * (1.f / 256.f) - mu * mu;
            stat[r][0] = mu; stat[r][1] = rsqrtf(var + EPSF);
        }
    }
    __syncthreads();
    for (int e = tid; e < 4096; e += 256) {
        int r = e >> 8, c = e & 255;
        tf[r][c] = (tf[r][c] - stat[r][0]) * stat[r][1] * lnf_g[c] + lnf_b[c];
    }
    __syncthreads();
    if (nb < 5760) {
        float acc[16];
#pragma unroll
        for (int bb = 0; bb < 16; bb++) acc[bb] = 0.f;
        for (int k = 0; k < 256; k++) {
            float wv = fin_w[(size_t)k * 5760 + nb];
#pragma unroll
            for (int bb = 0; bb < 16; bb++) acc[bb] += tf[bb][k] * wv;
        }
        float fb = fin_b[nb];
#pragma unroll
        for (int bb = 0; bb < 16; bb++)
            refined5[(size_t)(bg + bb) * 5760 + nb] = acc[bb] + fb;
    }
}

// ---------------------------------------------------------------------------
extern "C" void kernel_launch(void* const* d_in, const int* in_sizes, int n_in,
                              void* d_out, int out_size, void* d_ws, size_t ws_size,
                              hipStream_t stream)
{
    const float* x      = (const float*)d_in[0];
    const float* ext_w1 = (const float*)d_in[1];
    const float* ext_b1 = (const float*)d_in[2];
    const float* ext_g  = (const float*)d_in[3];
    const float* ext_bb = (const float*)d_in[4];
    const float* ext_m  = (const float*)d_in[5];
    const float* ext_v  = (const float*)d_in[6];
    const float* ext_w2 = (const float*)d_in[7];
    const float* ext_b2 = (const float*)d_in[8];
    const float* cls_w1 = (const float*)d_in[9];
    const float* cls_b1 = (const float*)d_in[10];
    const float* cls_g  = (const float*)d_in[11];
    const float* cls_bb = (const float*)d_in[12];
    const float* cls_m  = (const float*)d_in[13];
    const float* cls_v  = (const float*)d_in[14];
    const float* cls_w2 = (const float*)d_in[15];
    const float* cls_b2 = (const float*)d_in[16];
    const float* tok_w  = (const float*)d_in[17];
    const float* tok_b  = (const float*)d_in[18];
    const float* emb    = (const float*)d_in[19];
    const float* ln1_g  = (const float*)d_in[20];
    const float* ln1_b  = (const float*)d_in[21];
    const float* qkv_w  = (const float*)d_in[22];
    const float* out_w  = (const float*)d_in[23];
    const float* out_b  = (const float*)d_in[24];
    const float* ln2_g  = (const float*)d_in[25];
    const float* ln2_b  = (const float*)d_in[26];
    const float* ff_w1  = (const float*)d_in[27];
    const float* ff_b1  = (const float*)d_in[28];
    const float* ff_w2  = (const float*)d_in[29];
    const float* ff_b2  = (const float*)d_in[30];
    const float* lnf_g  = (const float*)d_in[31];
    const float* lnf_b  = (const float*)d_in[32];
    const float* fin_w  = (const float*)d_in[33];
    const float* fin_b  = (const float*)d_in[34];

    float* out = (float*)d_out;
    float* ws  = (float*)d_ws;

    // workspace layout (float offsets)
    float*  Wc32     = ws;                        // 184320
    float*  cconst   = ws + 184320;               // 160
    ushort* Wchi     = (ushort*)(ws + 184480);    // 92160 floats
    ushort* Wclo     = (ushort*)(ws + 276640);    // 92160 floats
    float*  logitsP  = ws + 368800;               // 2*18432*160 = 5898240
    float*  partials = ws + 6267040;              // 4608
    float*  refined5 = ws + 6435488;              // 737280
    float*  tpart    = ws + 7172768;              // 262144
    int*    amax     = (int*)(ws + 7434912);      // 18432
    int*    flag     = (int*)(ws + 7453344);      // 1
    int*    cand_cnt = (int*)(ws + 7453345);      // 1
    int*    cand_lst = (int*)(ws + 7453346);      // 18432
    float*  w1cT     = ws + 7471780;              // 294912
    float*  w2cT     = ws + 7766692;              // 36864
    float*  WcT      = ws + 7803556;              // 184320
    float*  sbuf     = ws + 8184484;              // 32768
    float*  qkbuf    = ws + 8217252;              // 147456
    float*  z2_5     = ws + 8364708;              // 32768
    float*  t5buf    = ws + 8397476;              // 32768
    float*  f5buf    = ws + 8430244;              // 65536
    float*  t6buf    = ws + 8495780;              // 32768 -> ends 8528548

    // output offsets: ext | cls | ext2 | cls2
    float* out_ext  = out;
    float* out_cls  = out + 36864;
    float* out_ext2 = out + 2691072;
    float* out_cls2 = out + 2727936;

    dim3 blk(256);

    // weight prep (independent of x); also zeroes cand_cnt
    wcomb_build<<<dim3(160, 4), blk, 0, stream>>>(
        ext_w1, ext_b1, ext_g, ext_bb, ext_m, ext_v, ext_w2, ext_b2,
        cls_w1, cls_b1, cls_g, cls_bb, cls_m, cls_v, cls_w2, cls_b2,
        Wc32, Wchi, Wclo, cconst, cand_cnt);
    transpose3<<<dim3(36, 8, 3), blk, 0, stream>>>(cls_w1, w1cT, cls_w2, w2cT, Wc32, WcT);

    // pass 1
    logits_gemm<<<dim3(288, NKS), blk, 0, stream>>>(x, Wchi, Wclo, logitsP);
    softmax_heads<0><<<4608, blk, 0, stream>>>(logitsP, cconst, out_cls, out_ext, amax, partials,
        cand_cnt, cand_lst, nullptr, nullptr, nullptr, nullptr);
    reduce_flag<<<1, blk, 0, stream>>>(partials, 4608, flag);
    fixup_list<<<256, blk, 0, stream>>>(cand_cnt, cand_lst, x,
        w1cT, cls_b1, cls_g, cls_bb, cls_m, cls_v, w2cT, cls_b2, amax);

    // refine chain (always computed; application predicated on flag)
    tok_partial<<<dim3(128, 8), blk, 0, stream>>>(x, amax, tok_w, tpart);
    qkv_gemm<<<dim3(128, 7), blk, 0, stream>>>(tpart, tok_b, emb, ln1_g, ln1_b, qkv_w,
        qkbuf, sbuf);
    attn_out<<<128, blk, 0, stream>>>(qkbuf, sbuf, emb, out_w, out_b, ln2_g, ln2_b, z2_5, t5buf);
    ff1_gelu<<<dim3(128, 4), blk, 0, stream>>>(z2_5, ff_w1, ff_b1, f5buf);
    ff2_half<<<dim3(128, 2), blk, 0, stream>>>(f5buf, ff_w2, ff_b2, t5buf, t6buf);
    fin_gemm<<<dim3(23, 8), blk, 0, stream>>>(t6buf, lnf_g, lnf_b, fin_w, fin_b, refined5);

    // pass 2 = pass 1 logits + rank-40 delta fused into softmax
    softmax_heads<1><<<4608, blk, 0, stream>>>(logitsP, cconst, out_cls2, out_ext2, amax, nullptr,
        nullptr, nullptr, x, WcT, refined5, flag);
}